// Round 2
// baseline (53485.089 us; speedup 1.0000x reference)
//
#include <hip/hip_runtime.h>
#include <stdint.h>

#define N_ROWS 100000
#define D_IN 512
#define H_DIM 2048
#define HEADS 4
#define NSEG 10000

typedef unsigned short u16;
typedef __attribute__((ext_vector_type(4))) float f32x4;
typedef __attribute__((ext_vector_type(8))) __bf16 bf16x8;
typedef __attribute__((ext_vector_type(8))) u16 u16x8;
typedef __attribute__((ext_vector_type(4))) u16 u16x4;

__device__ __forceinline__ u16 f2bf(float f) {
  union { float f; uint32_t u; } v; v.f = f;
  uint32_t r = (v.u + 0x7FFF + ((v.u >> 16) & 1)) >> 16;
  return (u16)r;
}
__device__ __forceinline__ float bf2f(u16 u) {
  union { uint32_t u; float f; } v; v.u = ((uint32_t)u) << 16;
  return v.f;
}

// ---------------- init: bias1 = b1 + alpha*W1[512,:], zero segmax/segsum ---
__global__ void init_misc(const float* __restrict__ W1, const float* __restrict__ b1,
                          const float* __restrict__ alpha, float* __restrict__ bias1,
                          float* __restrict__ segmax, float* __restrict__ segsum) {
  int i = blockIdx.x * 256 + threadIdx.x;
  if (i < NSEG * HEADS) { segmax[i] = 0.f; segsum[i] = 0.f; }
  if (i < H_DIM) bias1[i] = b1[i] + alpha[0] * W1[(size_t)D_IN * H_DIM + i];
}

// ---------------- cast x (fp32) -> xb (bf16) -------------------------------
__global__ void cast_x_kernel(const float* __restrict__ x, u16* __restrict__ xb, long n4) {
  long i = (long)blockIdx.x * 256 + threadIdx.x;
  if (i >= n4) return;
  f32x4 v = *(const f32x4*)(x + i * 4);
  u16x4 o;
  o[0] = f2bf(v[0]); o[1] = f2bf(v[1]); o[2] = f2bf(v[2]); o[3] = f2bf(v[3]);
  *(u16x4*)(xb + i * 4) = o;
}

// ---------------- transpose + cast: in[R][C] fp32 -> out[C][R] bf16 --------
__global__ __launch_bounds__(256) void transpose_cast(const float* __restrict__ in,
                                                      u16* __restrict__ outT,
                                                      int R, int Cc) {
  __shared__ float t[32][33];
  const int c0 = blockIdx.x * 32, r0 = blockIdx.y * 32;
  const int tx = threadIdx.x, ty = threadIdx.y;  // 32 x 8
#pragma unroll
  for (int i = 0; i < 4; ++i)
    t[ty + 8 * i][tx] = in[(size_t)(r0 + ty + 8 * i) * Cc + c0 + tx];
  __syncthreads();
#pragma unroll
  for (int i = 0; i < 4; ++i) {
    int oc = ty + 8 * i;
    outT[(size_t)(c0 + oc) * R + r0 + tx] = f2bf(t[tx][oc]);
  }
}

// ---------------- NT GEMM: C[M,Nc] = act(A[M,K] @ Bt[Nc,K]^T + bias) -------
// 128x128 tile, BK=32, 4 waves, mfma_f32_16x16x32_bf16 (m97 structure)
template <int RELU>
__global__ __launch_bounds__(256) void gemm_nt(const u16* __restrict__ A,
                                               const u16* __restrict__ Bt,
                                               const float* __restrict__ bias,
                                               u16* __restrict__ C,
                                               int M, int Nc, int K) {
  __shared__ __align__(16) u16 As[128 * 32];
  __shared__ __align__(16) u16 Bs[128 * 32];
  const int tid = threadIdx.x;
  const int w = tid >> 6, l = tid & 63;
  const int wr = w >> 1, wc = w & 1;
  const int lr = l & 15, g = l >> 4;
  const int rowBase = blockIdx.y * 128, colBase = blockIdx.x * 128;

  f32x4 acc[4][4] = {};

  for (int k0 = 0; k0 < K; k0 += 32) {
    __syncthreads();
#pragma unroll
    for (int it = 0; it < 2; ++it) {
      const int ci = it * 256 + tid;          // this lane's 16B chunk id (0..511)
      const int cbase = it * 256 + (w << 6);  // wave-uniform chunk base
      {
        int r = ci >> 2, c = (ci & 3) * 8;
        int gr = rowBase + r;
        if (gr >= M) gr = M - 1;
        const u16* src = A + (size_t)gr * K + k0 + c;
        __builtin_amdgcn_global_load_lds(
            (const __attribute__((address_space(1))) void*)src,
            (__attribute__((address_space(3))) void*)(As + (size_t)cbase * 8),
            16, 0, 0);
      }
      {
        int n_ = ci >> 2, c = (ci & 3) * 8;
        const u16* src = Bt + (size_t)(colBase + n_) * K + k0 + c;
        __builtin_amdgcn_global_load_lds(
            (const __attribute__((address_space(1))) void*)src,
            (__attribute__((address_space(3))) void*)(Bs + (size_t)cbase * 8),
            16, 0, 0);
      }
    }
    __syncthreads();

    bf16x8 af[4], bfr[4];
#pragma unroll
    for (int mi = 0; mi < 4; ++mi)
      af[mi] = *(const bf16x8*)(As + (wr * 64 + mi * 16 + lr) * 32 + g * 8);
#pragma unroll
    for (int ni = 0; ni < 4; ++ni)
      bfr[ni] = *(const bf16x8*)(Bs + (wc * 64 + ni * 16 + lr) * 32 + g * 8);
#pragma unroll
    for (int mi = 0; mi < 4; ++mi)
#pragma unroll
      for (int ni = 0; ni < 4; ++ni)
        acc[mi][ni] = __builtin_amdgcn_mfma_f32_16x16x32_bf16(af[mi], bfr[ni], acc[mi][ni], 0, 0, 0);
  }

  float bv[4];
#pragma unroll
  for (int ni = 0; ni < 4; ++ni) bv[ni] = bias[colBase + wc * 64 + ni * 16 + lr];
#pragma unroll
  for (int mi = 0; mi < 4; ++mi) {
#pragma unroll
    for (int r = 0; r < 4; ++r) {
      int row = rowBase + wr * 64 + mi * 16 + g * 4 + r;
      if (row < M) {
#pragma unroll
        for (int ni = 0; ni < 4; ++ni) {
          float v = acc[mi][ni][r] + bv[ni];
          if (RELU) v = fmaxf(v, 0.f);
          C[(size_t)row * Nc + colBase + wc * 64 + ni * 16 + lr] = f2bf(v);
        }
      }
    }
  }
}

// ---------------- LayerNorm + 4-head projection + sigmoid + seg-max --------
// row ids are int32 (harness passes integer inputs as int)
__global__ __launch_bounds__(256) void ln_att_kernel(
    const u16* __restrict__ h2, const float* __restrict__ gam,
    const float* __restrict__ bet, const float* __restrict__ Wa,
    const float* __restrict__ ba, const int* __restrict__ row,
    float* __restrict__ att, float* __restrict__ segmax, int rows) {
  const int w = threadIdx.x >> 6, l = threadIdx.x & 63;
  const int n = blockIdx.x * 4 + w;
  if (n >= rows) return;
  const u16* hp = h2 + (size_t)n * D_IN + l * 8;
  u16x8 hraw = *(const u16x8*)hp;
  float hv[8];
  float s = 0.f, sq = 0.f;
#pragma unroll
  for (int j = 0; j < 8; ++j) {
    hv[j] = bf2f(hraw[j]);
    s += hv[j];
    sq += hv[j] * hv[j];
  }
#pragma unroll
  for (int off = 32; off >= 1; off >>= 1) {
    s += __shfl_xor(s, off);
    sq += __shfl_xor(sq, off);
  }
  const float mean = s * (1.f / 512.f);
  const float var = sq * (1.f / 512.f) - mean * mean;
  const float rstd = rsqrtf(var + 1e-5f);
  float a0 = 0, a1 = 0, a2 = 0, a3 = 0;
#pragma unroll
  for (int j = 0; j < 8; ++j) {
    int d = l * 8 + j;
    float hn = (hv[j] - mean) * rstd * gam[d] + bet[d];
    f32x4 wv = *(const f32x4*)(Wa + (size_t)d * 4);
    a0 += hn * wv[0]; a1 += hn * wv[1]; a2 += hn * wv[2]; a3 += hn * wv[3];
  }
#pragma unroll
  for (int off = 32; off >= 1; off >>= 1) {
    a0 += __shfl_xor(a0, off); a1 += __shfl_xor(a1, off);
    a2 += __shfl_xor(a2, off); a3 += __shfl_xor(a3, off);
  }
  if (l == 0) {
    int rid = row[n];
    float av[4] = {a0, a1, a2, a3};
#pragma unroll
    for (int h = 0; h < 4; ++h) {
      float z = av[h] + ba[h];
      float sg = 1.f / (1.f + expf(-z));
      att[(size_t)n * 4 + h] = sg;
      atomicMax((int*)&segmax[(size_t)rid * 4 + h], __float_as_int(sg));  // sg > 0 always
    }
  }
}

// ---------------- segment sum of exp ---------------------------------------
__global__ void seg_exp_sum(const float* __restrict__ att, const int* __restrict__ row,
                            const float* __restrict__ segmax, float* __restrict__ segsum) {
  int i = blockIdx.x * 256 + threadIdx.x;
  if (i >= N_ROWS * HEADS) return;
  int n = i >> 2, h = i & 3;
  int rid = row[n];
  float ev = expf(att[i] - segmax[(size_t)rid * 4 + h]);
  atomicAdd(&segsum[(size_t)rid * 4 + h], ev);
}

// ---------------- normalize + head-mean ------------------------------------
__global__ void seg_norm(const float* __restrict__ att, const int* __restrict__ row,
                         const float* __restrict__ segmax, const float* __restrict__ segsum,
                         float* __restrict__ out) {
  int n = blockIdx.x * 256 + threadIdx.x;
  if (n >= N_ROWS) return;
  int rid = row[n];
  float s = 0.f;
#pragma unroll
  for (int h = 0; h < 4; ++h) {
    float ev = expf(att[(size_t)n * 4 + h] - segmax[(size_t)rid * 4 + h]);
    s += ev / segsum[(size_t)rid * 4 + h];
  }
  out[n] = 0.25f * s;
}

extern "C" void kernel_launch(void* const* d_in, const int* in_sizes, int n_in,
                              void* d_out, int out_size, void* d_ws, size_t ws_size,
                              hipStream_t stream) {
  const float* x = (const float*)d_in[0];
  const int* row = (const int*)d_in[1];
  const float* alpha = (const float*)d_in[2];
  const float* W1 = (const float*)d_in[3];
  const float* b1 = (const float*)d_in[4];
  const float* W2 = (const float*)d_in[5];
  const float* b2 = (const float*)d_in[6];
  const float* ln_g = (const float*)d_in[7];
  const float* ln_b = (const float*)d_in[8];
  const float* Wa = (const float*)d_in[9];
  const float* ba = (const float*)d_in[10];
  float* out = (float*)d_out;

  char* ws = (char*)d_ws;
  size_t off = 0;
  auto alloc = [&](size_t bytes) {
    void* p = ws + off;
    off += (bytes + 255) & ~(size_t)255;
    return p;
  };
  // fixed buffers (~8 MB)
  u16* W1t = (u16*)alloc((size_t)H_DIM * D_IN * 2);
  u16* W2t = (u16*)alloc((size_t)D_IN * H_DIM * 2);
  float* bias1 = (float*)alloc(H_DIM * 4);
  float* att = (float*)alloc((size_t)N_ROWS * HEADS * 4);
  float* segmax = (float*)alloc(NSEG * HEADS * 4);
  float* segsum = (float*)alloc(NSEG * HEADS * 4);

  // slab size chosen from remaining workspace: per-row 6144 B (xb+h1+h2)
  const size_t per_row = ((size_t)D_IN + H_DIM + D_IN) * 2;
  size_t usable = (ws_size > off + (size_t)16 << 20) ? (ws_size - off - ((size_t)4 << 20)) : 0;
  long slab_l = (long)(usable / per_row);
  int slab = (int)(slab_l > N_ROWS ? N_ROWS : slab_l);
  slab = (slab + 127) & ~127;          // round to tile multiple
  if (slab < 128) slab = 128;          // last-resort minimum
  if (slab > ((N_ROWS + 127) & ~127)) slab = (N_ROWS + 127) & ~127;

  u16* xb = (u16*)alloc((size_t)slab * D_IN * 2);
  u16* h1 = (u16*)alloc((size_t)slab * H_DIM * 2);
  u16* h2 = (u16*)alloc((size_t)slab * D_IN * 2);

  init_misc<<<(NSEG * HEADS + 255) / 256, 256, 0, stream>>>(W1, b1, alpha, bias1, segmax, segsum);
  transpose_cast<<<dim3(H_DIM / 32, D_IN / 32), dim3(32, 8), 0, stream>>>(W1, W1t, D_IN, H_DIM);
  transpose_cast<<<dim3(D_IN / 32, H_DIM / 32), dim3(32, 8), 0, stream>>>(W2, W2t, H_DIM, D_IN);

  for (int s0 = 0; s0 < N_ROWS; s0 += slab) {
    int rows = N_ROWS - s0 < slab ? N_ROWS - s0 : slab;
    long n4 = (long)rows * D_IN / 4;
    cast_x_kernel<<<(int)((n4 + 255) / 256), 256, 0, stream>>>(x + (size_t)s0 * D_IN, xb, n4);
    gemm_nt<1><<<dim3(H_DIM / 128, (rows + 127) / 128), 256, 0, stream>>>(
        xb, W1t, bias1, h1, rows, H_DIM, D_IN);
    gemm_nt<1><<<dim3(D_IN / 128, (rows + 127) / 128), 256, 0, stream>>>(
        h1, W2t, b2, h2, rows, D_IN, H_DIM);
    ln_att_kernel<<<(rows + 3) / 4, 256, 0, stream>>>(
        h2, ln_g, ln_b, Wa, ba, row + s0, att + (size_t)s0 * HEADS, segmax, rows);
  }

  seg_exp_sum<<<(N_ROWS * HEADS + 255) / 256, 256, 0, stream>>>(att, row, segmax, segsum);
  seg_norm<<<(N_ROWS + 255) / 256, 256, 0, stream>>>(att, row, segmax, segsum, out);
}

// Round 3
// 900.222 us; speedup vs baseline: 59.4132x; 59.4132x over previous
//
#include <hip/hip_runtime.h>
#include <stdint.h>

#define N_ROWS 100000
#define D_IN 512
#define H_DIM 2048
#define HEADS 4
#define NSEG 10000

typedef unsigned short u16;
typedef __attribute__((ext_vector_type(4))) float f32x4;
typedef __attribute__((ext_vector_type(8))) __bf16 bf16x8;
typedef __attribute__((ext_vector_type(8))) u16 u16x8;
typedef __attribute__((ext_vector_type(4))) u16 u16x4;

__device__ __forceinline__ u16 f2bf(float f) {
  union { float f; uint32_t u; } v; v.f = f;
  uint32_t r = (v.u + 0x7FFF + ((v.u >> 16) & 1)) >> 16;
  return (u16)r;
}
__device__ __forceinline__ float bf2f(u16 u) {
  union { uint32_t u; float f; } v; v.u = ((uint32_t)u) << 16;
  return v.f;
}

// ---------------- init: bias1 = b1 + alpha*W1[512,:], zero segmax/segsum ---
__global__ void init_misc(const float* __restrict__ W1, const float* __restrict__ b1,
                          const float* __restrict__ alpha, float* __restrict__ bias1,
                          float* __restrict__ segmax, float* __restrict__ segsum) {
  int i = blockIdx.x * 256 + threadIdx.x;
  if (i < NSEG * HEADS) { segmax[i] = 0.f; segsum[i] = 0.f; }
  if (i < H_DIM) bias1[i] = b1[i] + alpha[0] * W1[(size_t)D_IN * H_DIM + i];
}

// ---------------- cast x (fp32) -> xb (bf16) -------------------------------
__global__ void cast_x_kernel(const float* __restrict__ x, u16* __restrict__ xb, long n4) {
  long i = (long)blockIdx.x * 256 + threadIdx.x;
  if (i >= n4) return;
  f32x4 v = *(const f32x4*)(x + i * 4);
  u16x4 o;
  o[0] = f2bf(v[0]); o[1] = f2bf(v[1]); o[2] = f2bf(v[2]); o[3] = f2bf(v[3]);
  *(u16x4*)(xb + i * 4) = o;
}

// ---------------- transpose + cast: in[R][C] fp32 -> out[C][R] bf16 --------
__global__ __launch_bounds__(256) void transpose_cast(const float* __restrict__ in,
                                                      u16* __restrict__ outT,
                                                      int R, int Cc) {
  __shared__ float t[32][33];
  const int c0 = blockIdx.x * 32, r0 = blockIdx.y * 32;
  const int tx = threadIdx.x, ty = threadIdx.y;  // 32 x 8
#pragma unroll
  for (int i = 0; i < 4; ++i)
    t[ty + 8 * i][tx] = in[(size_t)(r0 + ty + 8 * i) * Cc + c0 + tx];
  __syncthreads();
#pragma unroll
  for (int i = 0; i < 4; ++i) {
    int oc = ty + 8 * i;
    outT[(size_t)(c0 + oc) * R + r0 + tx] = f2bf(t[tx][oc]);
  }
}

// ---------------- NT GEMM: C[M,Nc] = act(A[M,K] @ Bt[Nc,K]^T + bias) -------
// 128x128 tile, BK=32, 4 waves, mfma_f32_16x16x32_bf16 (m97 structure)
template <int RELU>
__global__ __launch_bounds__(256) void gemm_nt(const u16* __restrict__ A,
                                               const u16* __restrict__ Bt,
                                               const float* __restrict__ bias,
                                               u16* __restrict__ C,
                                               int M, int Nc, int K) {
  __shared__ __align__(16) u16 As[128 * 32];
  __shared__ __align__(16) u16 Bs[128 * 32];
  const int tid = threadIdx.x;
  const int w = tid >> 6, l = tid & 63;
  const int wr = w >> 1, wc = w & 1;
  const int lr = l & 15, g = l >> 4;
  const int rowBase = blockIdx.y * 128, colBase = blockIdx.x * 128;

  f32x4 acc[4][4] = {};

  for (int k0 = 0; k0 < K; k0 += 32) {
    __syncthreads();
#pragma unroll
    for (int it = 0; it < 2; ++it) {
      const int ci = it * 256 + tid;          // this lane's 16B chunk id (0..511)
      const int cbase = it * 256 + (w << 6);  // wave-uniform chunk base
      {
        int r = ci >> 2, c = (ci & 3) * 8;
        int gr = rowBase + r;
        if (gr >= M) gr = M - 1;
        const u16* src = A + (size_t)gr * K + k0 + c;
        __builtin_amdgcn_global_load_lds(
            (const __attribute__((address_space(1))) void*)src,
            (__attribute__((address_space(3))) void*)(As + (size_t)cbase * 8),
            16, 0, 0);
      }
      {
        int n_ = ci >> 2, c = (ci & 3) * 8;
        const u16* src = Bt + (size_t)(colBase + n_) * K + k0 + c;
        __builtin_amdgcn_global_load_lds(
            (const __attribute__((address_space(1))) void*)src,
            (__attribute__((address_space(3))) void*)(Bs + (size_t)cbase * 8),
            16, 0, 0);
      }
    }
    __syncthreads();

    bf16x8 af[4], bfr[4];
#pragma unroll
    for (int mi = 0; mi < 4; ++mi)
      af[mi] = *(const bf16x8*)(As + (wr * 64 + mi * 16 + lr) * 32 + g * 8);
#pragma unroll
    for (int ni = 0; ni < 4; ++ni)
      bfr[ni] = *(const bf16x8*)(Bs + (wc * 64 + ni * 16 + lr) * 32 + g * 8);
#pragma unroll
    for (int mi = 0; mi < 4; ++mi)
#pragma unroll
      for (int ni = 0; ni < 4; ++ni)
        acc[mi][ni] = __builtin_amdgcn_mfma_f32_16x16x32_bf16(af[mi], bfr[ni], acc[mi][ni], 0, 0, 0);
  }

  float bv[4];
#pragma unroll
  for (int ni = 0; ni < 4; ++ni) bv[ni] = bias[colBase + wc * 64 + ni * 16 + lr];
#pragma unroll
  for (int mi = 0; mi < 4; ++mi) {
#pragma unroll
    for (int r = 0; r < 4; ++r) {
      int row = rowBase + wr * 64 + mi * 16 + g * 4 + r;
      if (row < M) {
#pragma unroll
        for (int ni = 0; ni < 4; ++ni) {
          float v = acc[mi][ni][r] + bv[ni];
          if (RELU) v = fmaxf(v, 0.f);
          C[(size_t)row * Nc + colBase + wc * 64 + ni * 16 + lr] = f2bf(v);
        }
      }
    }
  }
}

// ---------------- LayerNorm + 4-head projection + sigmoid + seg-max --------
__global__ __launch_bounds__(256) void ln_att_kernel(
    const u16* __restrict__ h2, const float* __restrict__ gam,
    const float* __restrict__ bet, const float* __restrict__ Wa,
    const float* __restrict__ ba, const int* __restrict__ row,
    float* __restrict__ att, float* __restrict__ segmax, int rows) {
  const int w = threadIdx.x >> 6, l = threadIdx.x & 63;
  const int n = blockIdx.x * 4 + w;
  if (n >= rows) return;
  const u16* hp = h2 + (size_t)n * D_IN + l * 8;
  u16x8 hraw = *(const u16x8*)hp;
  float hv[8];
  float s = 0.f, sq = 0.f;
#pragma unroll
  for (int j = 0; j < 8; ++j) {
    hv[j] = bf2f(hraw[j]);
    s += hv[j];
    sq += hv[j] * hv[j];
  }
#pragma unroll
  for (int off = 32; off >= 1; off >>= 1) {
    s += __shfl_xor(s, off);
    sq += __shfl_xor(sq, off);
  }
  const float mean = s * (1.f / 512.f);
  const float var = sq * (1.f / 512.f) - mean * mean;
  const float rstd = rsqrtf(var + 1e-5f);
  float a0 = 0, a1 = 0, a2 = 0, a3 = 0;
#pragma unroll
  for (int j = 0; j < 8; ++j) {
    int d = l * 8 + j;
    float hn = (hv[j] - mean) * rstd * gam[d] + bet[d];
    f32x4 wv = *(const f32x4*)(Wa + (size_t)d * 4);
    a0 += hn * wv[0]; a1 += hn * wv[1]; a2 += hn * wv[2]; a3 += hn * wv[3];
  }
#pragma unroll
  for (int off = 32; off >= 1; off >>= 1) {
    a0 += __shfl_xor(a0, off); a1 += __shfl_xor(a1, off);
    a2 += __shfl_xor(a2, off); a3 += __shfl_xor(a3, off);
  }
  if (l == 0) {
    int rid = row[n];
    float av[4] = {a0, a1, a2, a3};
#pragma unroll
    for (int h = 0; h < 4; ++h) {
      float z = av[h] + ba[h];
      float sg = 1.f / (1.f + expf(-z));
      att[(size_t)n * 4 + h] = sg;
      atomicMax((int*)&segmax[(size_t)rid * 4 + h], __float_as_int(sg));  // sg > 0 always
    }
  }
}

// ---------------- segment sum of exp ---------------------------------------
__global__ void seg_exp_sum(const float* __restrict__ att, const int* __restrict__ row,
                            const float* __restrict__ segmax, float* __restrict__ segsum) {
  int i = blockIdx.x * 256 + threadIdx.x;
  if (i >= N_ROWS * HEADS) return;
  int n = i >> 2, h = i & 3;
  int rid = row[n];
  float ev = expf(att[i] - segmax[(size_t)rid * 4 + h]);
  atomicAdd(&segsum[(size_t)rid * 4 + h], ev);
}

// ---------------- normalize + head-mean ------------------------------------
__global__ void seg_norm(const float* __restrict__ att, const int* __restrict__ row,
                         const float* __restrict__ segmax, const float* __restrict__ segsum,
                         float* __restrict__ out) {
  int n = blockIdx.x * 256 + threadIdx.x;
  if (n >= N_ROWS) return;
  int rid = row[n];
  float s = 0.f;
#pragma unroll
  for (int h = 0; h < 4; ++h) {
    float ev = expf(att[(size_t)n * 4 + h] - segmax[(size_t)rid * 4 + h]);
    s += ev / segsum[(size_t)rid * 4 + h];
  }
  out[n] = 0.25f * s;
}

extern "C" void kernel_launch(void* const* d_in, const int* in_sizes, int n_in,
                              void* d_out, int out_size, void* d_ws, size_t ws_size,
                              hipStream_t stream) {
  const float* x = (const float*)d_in[0];
  const int* row = (const int*)d_in[1];
  const float* alpha = (const float*)d_in[2];
  const float* W1 = (const float*)d_in[3];
  const float* b1 = (const float*)d_in[4];
  const float* W2 = (const float*)d_in[5];
  const float* b2 = (const float*)d_in[6];
  const float* ln_g = (const float*)d_in[7];
  const float* ln_b = (const float*)d_in[8];
  const float* Wa = (const float*)d_in[9];
  const float* ba = (const float*)d_in[10];
  float* out = (float*)d_out;

  char* ws = (char*)d_ws;
  size_t off = 0;
  auto alloc = [&](size_t bytes) {
    void* p = ws + off;
    off += (bytes + 255) & ~(size_t)255;
    return p;
  };
  // fixed buffers (~8 MB)
  u16* W1t = (u16*)alloc((size_t)H_DIM * D_IN * 2);
  u16* W2t = (u16*)alloc((size_t)D_IN * H_DIM * 2);
  float* bias1 = (float*)alloc(H_DIM * 4);
  float* att = (float*)alloc((size_t)N_ROWS * HEADS * 4);
  float* segmax = (float*)alloc(NSEG * HEADS * 4);
  float* segsum = (float*)alloc(NSEG * HEADS * 4);

  // slab sizing from remaining ws: per-row 6144 B (xb 1KB + h1 4KB + h2 1KB).
  // NOTE round-2 bug: `off + (size_t)16 << 20` == `(off+16)<<20` -> usable=0
  // -> slab=128 -> 3100 launches -> 53 ms. Parenthesized now.
  const size_t per_row = ((size_t)D_IN + H_DIM + D_IN) * 2;
  const size_t reserve = (size_t)1 << 20;
  size_t usable = (ws_size > off + reserve) ? (ws_size - off - reserve) : 0;
  long slab_l = (long)(usable / per_row);
  const int maxslab = (N_ROWS + 127) & ~127;  // 100096
  int slab;
  if (slab_l >= maxslab) slab = maxslab;
  else slab = (int)(slab_l & ~127L);          // round DOWN so allocs fit
  if (slab < 128) slab = 128;                 // last-resort minimum

  u16* xb = (u16*)alloc((size_t)slab * D_IN * 2);
  u16* h1 = (u16*)alloc((size_t)slab * H_DIM * 2);
  u16* h2 = (u16*)alloc((size_t)slab * D_IN * 2);

  init_misc<<<(NSEG * HEADS + 255) / 256, 256, 0, stream>>>(W1, b1, alpha, bias1, segmax, segsum);
  transpose_cast<<<dim3(H_DIM / 32, D_IN / 32), dim3(32, 8), 0, stream>>>(W1, W1t, D_IN, H_DIM);
  transpose_cast<<<dim3(D_IN / 32, H_DIM / 32), dim3(32, 8), 0, stream>>>(W2, W2t, H_DIM, D_IN);

  for (int s0 = 0; s0 < N_ROWS; s0 += slab) {
    int rows = N_ROWS - s0 < slab ? N_ROWS - s0 : slab;
    long n4 = (long)rows * D_IN / 4;
    cast_x_kernel<<<(int)((n4 + 255) / 256), 256, 0, stream>>>(x + (size_t)s0 * D_IN, xb, n4);
    gemm_nt<1><<<dim3(H_DIM / 128, (rows + 127) / 128), 256, 0, stream>>>(
        xb, W1t, bias1, h1, rows, H_DIM, D_IN);
    gemm_nt<1><<<dim3(D_IN / 128, (rows + 127) / 128), 256, 0, stream>>>(
        h1, W2t, b2, h2, rows, D_IN, H_DIM);
    ln_att_kernel<<<(rows + 3) / 4, 256, 0, stream>>>(
        h2, ln_g, ln_b, Wa, ba, row + s0, att + (size_t)s0 * HEADS, segmax, rows);
  }

  seg_exp_sum<<<(N_ROWS * HEADS + 255) / 256, 256, 0, stream>>>(att, row, segmax, segsum);
  seg_norm<<<(N_ROWS + 255) / 256, 256, 0, stream>>>(att, row, segmax, segsum, out);
}

// Round 4
// 788.372 us; speedup vs baseline: 67.8425x; 1.1419x over previous
//
#include <hip/hip_runtime.h>
#include <stdint.h>

#define N_ROWS 100000
#define D_IN 512
#define H_DIM 2048
#define HEADS 4
#define NSEG 10000

typedef unsigned short u16;
typedef __attribute__((ext_vector_type(4))) float f32x4;
typedef __attribute__((ext_vector_type(8))) __bf16 bf16x8;
typedef __attribute__((ext_vector_type(8))) u16 u16x8;
typedef __attribute__((ext_vector_type(4))) u16 u16x4;

__device__ __forceinline__ u16 f2bf(float f) {
  union { float f; uint32_t u; } v; v.f = f;
  uint32_t r = (v.u + 0x7FFF + ((v.u >> 16) & 1)) >> 16;
  return (u16)r;
}
__device__ __forceinline__ float bf2f(u16 u) {
  union { uint32_t u; float f; } v; v.u = ((uint32_t)u) << 16;
  return v.f;
}

// ---------------- init: bias1 = b1 + alpha*W1[512,:], zero segmax/segsum ---
__global__ void init_misc(const float* __restrict__ W1, const float* __restrict__ b1,
                          const float* __restrict__ alpha, float* __restrict__ bias1,
                          float* __restrict__ segmax, float* __restrict__ segsum) {
  int i = blockIdx.x * 256 + threadIdx.x;
  if (i < NSEG * HEADS) { segmax[i] = 0.f; segsum[i] = 0.f; }
  if (i < H_DIM) bias1[i] = b1[i] + alpha[0] * W1[(size_t)D_IN * H_DIM + i];
}

// ---------------- cast x (fp32) -> xb (bf16) -------------------------------
__global__ void cast_x_kernel(const float* __restrict__ x, u16* __restrict__ xb, long n4) {
  long i = (long)blockIdx.x * 256 + threadIdx.x;
  if (i >= n4) return;
  f32x4 v = *(const f32x4*)(x + i * 4);
  u16x4 o;
  o[0] = f2bf(v[0]); o[1] = f2bf(v[1]); o[2] = f2bf(v[2]); o[3] = f2bf(v[3]);
  *(u16x4*)(xb + i * 4) = o;
}

// ---------------- transpose + cast: in[R][C] fp32 -> out[C][R] bf16 --------
__global__ __launch_bounds__(256) void transpose_cast(const float* __restrict__ in,
                                                      u16* __restrict__ outT,
                                                      int R, int Cc) {
  __shared__ float t[32][33];
  const int c0 = blockIdx.x * 32, r0 = blockIdx.y * 32;
  const int tx = threadIdx.x, ty = threadIdx.y;  // 32 x 8
#pragma unroll
  for (int i = 0; i < 4; ++i)
    t[ty + 8 * i][tx] = in[(size_t)(r0 + ty + 8 * i) * Cc + c0 + tx];
  __syncthreads();
#pragma unroll
  for (int i = 0; i < 4; ++i) {
    int oc = ty + 8 * i;
    outT[(size_t)(c0 + oc) * R + r0 + tx] = f2bf(t[tx][oc]);
  }
}

// ---------------- NT GEMM: C[M,Nc] = act(A[M,K] @ Bt[Nc,K]^T + bias) -------
// 256x256 tile, BK=32, 8 waves (2x4), 4-slot LDS ring (128 KiB), counted
// vmcnt(8) gate + ONE s_barrier per K-step (T3/T4), XOR swizzle (T2),
// setprio (T5), bijective XCD swizzle (T1/m204).
// LDS slot s (32 KiB): A tile [256][32] bf16 at s*32768, B tile at +16384.
// Swizzle (involution, bits 7-8 -> bits 4-5): off ^= ((off>>7)&3)<<4.
template <int RELU>
__global__ __launch_bounds__(512, 2) void gemm256(const u16* __restrict__ A,
                                                  const u16* __restrict__ Bt,
                                                  const float* __restrict__ bias,
                                                  u16* __restrict__ C,
                                                  int M, int Nc, int K, int NTN) {
  __shared__ __align__(16) char smem[131072];
  const int tid = threadIdx.x;
  const int w = tid >> 6, l = tid & 63;
  const int wm = w >> 2, wn = w & 3;   // 2 x 4 waves
  const int lr = l & 15, g = l >> 4;

  // m204 bijective XCD swizzle on 1D grid
  const int nwg = gridDim.x;
  const int orig = blockIdx.x;
  const int qq = nwg >> 3, rr = nwg & 7, xcd = orig & 7, idx = orig >> 3;
  const int wgid = (xcd < rr ? xcd * (qq + 1) : rr * (qq + 1) + (xcd - rr) * qq) + idx;
  const int rowBase = (wgid / NTN) * 256;
  const int colBase = (wgid % NTN) * 256;

  const int NK = K >> 5;

  // staging source pre-swizzle (per-lane, step-invariant): lane's LDS slot
  // q = p*8192 + tid*16 receives global element at o = swz(q).
  int srow[2], skb[2];
#pragma unroll
  for (int p = 0; p < 2; ++p) {
    int q = p * 8192 + tid * 16;
    int o = q ^ (((q >> 7) & 3) << 4);
    srow[p] = o >> 6;        // row in [0,256)
    skb[p] = (o & 63) >> 1;  // k element in [0,32)
  }
  // frag-read swizzled k-offset: (g*16) ^ (((row>>1)&3)<<4), row&15==lr
  const int axk = (g ^ ((lr >> 1) & 3)) << 4;

  f32x4 acc[8][4] = {};

  auto stage = [&](int kt, int slot) {
    char* sa = smem + slot * 32768;
    char* sb = sa + 16384;
#pragma unroll
    for (int p = 0; p < 2; ++p) {
      int ar = rowBase + srow[p]; if (ar >= M) ar = M - 1;
      const u16* asrc = A + (size_t)ar * K + kt * 32 + skb[p];
      __builtin_amdgcn_global_load_lds(
          (const __attribute__((address_space(1))) void*)asrc,
          (__attribute__((address_space(3))) void*)(sa + p * 8192 + (w << 10)), 16, 0, 0);
      int bc = colBase + srow[p];
      const u16* bsrc = Bt + (size_t)bc * K + kt * 32 + skb[p];
      __builtin_amdgcn_global_load_lds(
          (const __attribute__((address_space(1))) void*)bsrc,
          (__attribute__((address_space(3))) void*)(sb + p * 8192 + (w << 10)), 16, 0, 0);
    }
  };

  // prologue: 3 steps in flight
#pragma unroll
  for (int p = 0; p < 3; ++p)
    if (p < NK) stage(p, p);

  for (int k = 0; k < NK; ++k) {
    // gate: step k's loads (all waves) complete; counted, never 0 mid-loop
    if (k <= NK - 3)      asm volatile("s_waitcnt vmcnt(8)" ::: "memory");
    else if (k == NK - 2) asm volatile("s_waitcnt vmcnt(4)" ::: "memory");
    else                  asm volatile("s_waitcnt vmcnt(0)" ::: "memory");
    asm volatile("s_barrier" ::: "memory");

    // stage k+3 into slot (k+3)&3 = (k-1)&3 (its readers all retired pre-barrier)
    if (k + 3 <= NK - 1) stage(k + 3, (k + 3) & 3);

    const char* sa = smem + (k & 3) * 32768;
    const char* sb = sa + 16384;
    bf16x8 af[8], bq[4];
#pragma unroll
    for (int ni = 0; ni < 4; ++ni)
      bq[ni] = *(const bf16x8*)(sb + ((wn * 64 + ni * 16 + lr) * 64 + axk));
#pragma unroll
    for (int mi = 0; mi < 8; ++mi)
      af[mi] = *(const bf16x8*)(sa + ((wm * 128 + mi * 16 + lr) * 64 + axk));
    __builtin_amdgcn_s_setprio(1);
#pragma unroll
    for (int mi = 0; mi < 8; ++mi)
#pragma unroll
      for (int ni = 0; ni < 4; ++ni)
        acc[mi][ni] = __builtin_amdgcn_mfma_f32_16x16x32_bf16(af[mi], bq[ni], acc[mi][ni], 0, 0, 0);
    __builtin_amdgcn_s_setprio(0);
  }

  // epilogue: bias + optional relu, bf16 store
  float bv[4];
#pragma unroll
  for (int ni = 0; ni < 4; ++ni) bv[ni] = bias[colBase + wn * 64 + ni * 16 + lr];
#pragma unroll
  for (int mi = 0; mi < 8; ++mi) {
#pragma unroll
    for (int r = 0; r < 4; ++r) {
      int row = rowBase + wm * 128 + mi * 16 + g * 4 + r;
      if (row < M) {
#pragma unroll
        for (int ni = 0; ni < 4; ++ni) {
          float v = acc[mi][ni][r] + bv[ni];
          if (RELU) v = fmaxf(v, 0.f);
          C[(size_t)row * Nc + colBase + wn * 64 + ni * 16 + lr] = f2bf(v);
        }
      }
    }
  }
}

// ---------------- LayerNorm + 4-head projection + sigmoid + seg-max --------
__global__ __launch_bounds__(256) void ln_att_kernel(
    const u16* __restrict__ h2, const float* __restrict__ gam,
    const float* __restrict__ bet, const float* __restrict__ Wa,
    const float* __restrict__ ba, const int* __restrict__ row,
    float* __restrict__ att, float* __restrict__ segmax, int rows) {
  const int w = threadIdx.x >> 6, l = threadIdx.x & 63;
  const int n = blockIdx.x * 4 + w;
  if (n >= rows) return;
  const u16* hp = h2 + (size_t)n * D_IN + l * 8;
  u16x8 hraw = *(const u16x8*)hp;
  float hv[8];
  float s = 0.f, sq = 0.f;
#pragma unroll
  for (int j = 0; j < 8; ++j) {
    hv[j] = bf2f(hraw[j]);
    s += hv[j];
    sq += hv[j] * hv[j];
  }
#pragma unroll
  for (int off = 32; off >= 1; off >>= 1) {
    s += __shfl_xor(s, off);
    sq += __shfl_xor(sq, off);
  }
  const float mean = s * (1.f / 512.f);
  const float var = sq * (1.f / 512.f) - mean * mean;
  const float rstd = rsqrtf(var + 1e-5f);
  float a0 = 0, a1 = 0, a2 = 0, a3 = 0;
#pragma unroll
  for (int j = 0; j < 8; ++j) {
    int d = l * 8 + j;
    float hn = (hv[j] - mean) * rstd * gam[d] + bet[d];
    f32x4 wv = *(const f32x4*)(Wa + (size_t)d * 4);
    a0 += hn * wv[0]; a1 += hn * wv[1]; a2 += hn * wv[2]; a3 += hn * wv[3];
  }
#pragma unroll
  for (int off = 32; off >= 1; off >>= 1) {
    a0 += __shfl_xor(a0, off); a1 += __shfl_xor(a1, off);
    a2 += __shfl_xor(a2, off); a3 += __shfl_xor(a3, off);
  }
  if (l == 0) {
    int rid = row[n];
    float av[4] = {a0, a1, a2, a3};
#pragma unroll
    for (int h = 0; h < 4; ++h) {
      float z = av[h] + ba[h];
      float sg = 1.f / (1.f + expf(-z));
      att[(size_t)n * 4 + h] = sg;
      atomicMax((int*)&segmax[(size_t)rid * 4 + h], __float_as_int(sg));  // sg > 0 always
    }
  }
}

// ---------------- segment sum of exp ---------------------------------------
__global__ void seg_exp_sum(const float* __restrict__ att, const int* __restrict__ row,
                            const float* __restrict__ segmax, float* __restrict__ segsum) {
  int i = blockIdx.x * 256 + threadIdx.x;
  if (i >= N_ROWS * HEADS) return;
  int n = i >> 2, h = i & 3;
  int rid = row[n];
  float ev = expf(att[i] - segmax[(size_t)rid * 4 + h]);
  atomicAdd(&segsum[(size_t)rid * 4 + h], ev);
}

// ---------------- normalize + head-mean ------------------------------------
__global__ void seg_norm(const float* __restrict__ att, const int* __restrict__ row,
                         const float* __restrict__ segmax, const float* __restrict__ segsum,
                         float* __restrict__ out) {
  int n = blockIdx.x * 256 + threadIdx.x;
  if (n >= N_ROWS) return;
  int rid = row[n];
  float s = 0.f;
#pragma unroll
  for (int h = 0; h < 4; ++h) {
    float ev = expf(att[(size_t)n * 4 + h] - segmax[(size_t)rid * 4 + h]);
    s += ev / segsum[(size_t)rid * 4 + h];
  }
  out[n] = 0.25f * s;
}

extern "C" void kernel_launch(void* const* d_in, const int* in_sizes, int n_in,
                              void* d_out, int out_size, void* d_ws, size_t ws_size,
                              hipStream_t stream) {
  const float* x = (const float*)d_in[0];
  const int* row = (const int*)d_in[1];
  const float* alpha = (const float*)d_in[2];
  const float* W1 = (const float*)d_in[3];
  const float* b1 = (const float*)d_in[4];
  const float* W2 = (const float*)d_in[5];
  const float* b2 = (const float*)d_in[6];
  const float* ln_g = (const float*)d_in[7];
  const float* ln_b = (const float*)d_in[8];
  const float* Wa = (const float*)d_in[9];
  const float* ba = (const float*)d_in[10];
  float* out = (float*)d_out;

  char* ws = (char*)d_ws;
  size_t off = 0;
  auto alloc = [&](size_t bytes) {
    void* p = ws + off;
    off += (bytes + 255) & ~(size_t)255;
    return p;
  };
  // fixed buffers (~8 MB)
  u16* W1t = (u16*)alloc((size_t)H_DIM * D_IN * 2);
  u16* W2t = (u16*)alloc((size_t)D_IN * H_DIM * 2);
  float* bias1 = (float*)alloc(H_DIM * 4);
  float* att = (float*)alloc((size_t)N_ROWS * HEADS * 4);
  float* segmax = (float*)alloc(NSEG * HEADS * 4);
  float* segsum = (float*)alloc(NSEG * HEADS * 4);

  // slab sizing from remaining ws: per-row 6144 B (xb 1KB + h1 4KB + h2 1KB)
  const size_t per_row = ((size_t)D_IN + H_DIM + D_IN) * 2;
  const size_t reserve = (size_t)1 << 20;
  size_t usable = (ws_size > off + reserve) ? (ws_size - off - reserve) : 0;
  long slab_l = (long)(usable / per_row);
  const int maxslab = (N_ROWS + 255) & ~255;  // 100096
  int slab;
  if (slab_l >= maxslab) slab = maxslab;
  else slab = (int)(slab_l & ~255L);          // round DOWN so allocs fit
  if (slab < 256) slab = 256;                 // last-resort minimum

  u16* xb = (u16*)alloc((size_t)slab * D_IN * 2);
  u16* h1 = (u16*)alloc((size_t)slab * H_DIM * 2);
  u16* h2 = (u16*)alloc((size_t)slab * D_IN * 2);

  init_misc<<<(NSEG * HEADS + 255) / 256, 256, 0, stream>>>(W1, b1, alpha, bias1, segmax, segsum);
  transpose_cast<<<dim3(H_DIM / 32, D_IN / 32), dim3(32, 8), 0, stream>>>(W1, W1t, D_IN, H_DIM);
  transpose_cast<<<dim3(D_IN / 32, H_DIM / 32), dim3(32, 8), 0, stream>>>(W2, W2t, H_DIM, D_IN);

  for (int s0 = 0; s0 < N_ROWS; s0 += slab) {
    int rows = N_ROWS - s0 < slab ? N_ROWS - s0 : slab;
    int ntm = (rows + 255) / 256;
    long n4 = (long)rows * D_IN / 4;
    cast_x_kernel<<<(int)((n4 + 255) / 256), 256, 0, stream>>>(x + (size_t)s0 * D_IN, xb, n4);
    gemm256<1><<<ntm * (H_DIM / 256), 512, 0, stream>>>(
        xb, W1t, bias1, h1, rows, H_DIM, D_IN, H_DIM / 256);
    gemm256<1><<<ntm * (D_IN / 256), 512, 0, stream>>>(
        h1, W2t, b2, h2, rows, D_IN, H_DIM, D_IN / 256);
    ln_att_kernel<<<(rows + 3) / 4, 256, 0, stream>>>(
        h2, ln_g, ln_b, Wa, ba, row + s0, att + (size_t)s0 * HEADS, segmax, rows);
  }

  seg_exp_sum<<<(N_ROWS * HEADS + 255) / 256, 256, 0, stream>>>(att, row, segmax, segsum);
  seg_norm<<<(N_ROWS + 255) / 256, 256, 0, stream>>>(att, row, segmax, segsum, out);
}

// Round 5
// 717.607 us; speedup vs baseline: 74.5325x; 1.0986x over previous
//
#include <hip/hip_runtime.h>
#include <stdint.h>

#define N_ROWS 100000
#define D_IN 512
#define H_DIM 2048
#define HEADS 4
#define NSEG 10000

typedef unsigned short u16;
typedef __attribute__((ext_vector_type(4))) float f32x4;
typedef __attribute__((ext_vector_type(8))) __bf16 bf16x8;
typedef __attribute__((ext_vector_type(8))) u16 u16x8;
typedef __attribute__((ext_vector_type(4))) u16 u16x4;

__device__ __forceinline__ u16 f2bf(float f) {
  union { float f; uint32_t u; } v; v.f = f;
  uint32_t r = (v.u + 0x7FFF + ((v.u >> 16) & 1)) >> 16;
  return (u16)r;
}
__device__ __forceinline__ float bf2f(u16 u) {
  union { uint32_t u; float f; } v; v.u = ((uint32_t)u) << 16;
  return v.f;
}

// ---------------- init: bias1 = b1 + alpha*W1[512,:], zero segmax/segsum ---
__global__ void init_misc(const float* __restrict__ W1, const float* __restrict__ b1,
                          const float* __restrict__ alpha, float* __restrict__ bias1,
                          float* __restrict__ segmax, float* __restrict__ segsum) {
  int i = blockIdx.x * 256 + threadIdx.x;
  if (i < NSEG * HEADS) { segmax[i] = 0.f; segsum[i] = 0.f; }
  if (i < H_DIM) bias1[i] = b1[i] + alpha[0] * W1[(size_t)D_IN * H_DIM + i];
}

// ---------------- cast x (fp32) -> xb (bf16) -------------------------------
__global__ void cast_x_kernel(const float* __restrict__ x, u16* __restrict__ xb, long n4) {
  long i = (long)blockIdx.x * 256 + threadIdx.x;
  if (i >= n4) return;
  f32x4 v = *(const f32x4*)(x + i * 4);
  u16x4 o;
  o[0] = f2bf(v[0]); o[1] = f2bf(v[1]); o[2] = f2bf(v[2]); o[3] = f2bf(v[3]);
  *(u16x4*)(xb + i * 4) = o;
}

// ---------------- transpose + cast: in[R][C] fp32 -> out[C][R] bf16 --------
__global__ __launch_bounds__(256) void transpose_cast(const float* __restrict__ in,
                                                      u16* __restrict__ outT,
                                                      int R, int Cc) {
  __shared__ float t[32][33];
  const int c0 = blockIdx.x * 32, r0 = blockIdx.y * 32;
  const int tx = threadIdx.x, ty = threadIdx.y;  // 32 x 8
#pragma unroll
  for (int i = 0; i < 4; ++i)
    t[ty + 8 * i][tx] = in[(size_t)(r0 + ty + 8 * i) * Cc + c0 + tx];
  __syncthreads();
#pragma unroll
  for (int i = 0; i < 4; ++i) {
    int oc = ty + 8 * i;
    outT[(size_t)(c0 + oc) * R + r0 + tx] = f2bf(t[tx][oc]);
  }
}

// ============================================================================
// NT GEMM, 8-phase schedule (m201 port): C[M,Nc] = act(A[M,K] @ Bt[Nc,K]^T + b)
// 256x256 tile, BK=64, 8 waves (2M x 4N), 2 dbuf slots (128 KiB LDS).
// Slot s: A[256][64] bf16 at s*65536 (row stride 128B), B at +32768.
// XOR swizzle: byte ^= ((row&7)<<4)  (involution on chunk bits 4-6).
// 4 phases per K-tile: (kk0,ni01) (kk0,ni23) (kk1,ni01) (kk1,ni23); each
// phase: ds_read subtile | stage one 16KiB half-tile of a future K-tile |
// barrier | lgkmcnt(0) | 16 MFMA (setprio) | barrier.
// Stage schedule (tile T, slot T&1): A-half0 @ (T-2).ph3, A-half1 @ (T-1).ph0,
// B-half0 @ (T-1).ph1, B-half1 @ (T-1).ph2.  Gate: vmcnt(2) at t.ph3 (only
// A-half0(t+2) allowed in flight) => tile t+1 fully landed. Race-safety: a
// region staged at phase p was last read at phase p-1, whose readers all
// drained (lgkmcnt(0)) before the phase-(p-1) trailing barrier.
// ============================================================================
#define BARX asm volatile("s_barrier" ::: "memory")
#define LGKM0 do { asm volatile("s_waitcnt lgkmcnt(0)" ::: "memory"); \
                   __builtin_amdgcn_sched_barrier(0); } while (0)
#define MFMA16(NB) do { \
  __builtin_amdgcn_s_setprio(1); \
  _Pragma("unroll") \
  for (int mi = 0; mi < 8; ++mi) { \
    acc[mi][NB] = __builtin_amdgcn_mfma_f32_16x16x32_bf16(af[mi], bq[0], acc[mi][NB], 0, 0, 0); \
    acc[mi][NB + 1] = __builtin_amdgcn_mfma_f32_16x16x32_bf16(af[mi], bq[1], acc[mi][NB + 1], 0, 0, 0); \
  } \
  __builtin_amdgcn_s_setprio(0); \
} while (0)

template <int RELU>
__global__ __launch_bounds__(512, 2) void gemm256p(const u16* __restrict__ A,
                                                   const u16* __restrict__ Bt,
                                                   const float* __restrict__ bias,
                                                   u16* __restrict__ C,
                                                   int M, int Nc, int K, int NTN) {
  __shared__ __align__(16) char smem[131072];
  const int tid = threadIdx.x;
  const int w = tid >> 6, l = tid & 63;
  const int wm = w >> 2, wn = w & 3;  // 2 x 4 waves
  const int lr = l & 15, g = l >> 4;

  // T1: bijective XCD swizzle (m204)
  const int nwg = gridDim.x;
  const int orig = blockIdx.x;
  const int qq = nwg >> 3, rr = nwg & 7, xcd = orig & 7, idx = orig >> 3;
  const int wgid = (xcd < rr ? xcd * (qq + 1) : rr * (qq + 1) + (xcd - rr) * qq) + idx;
  const int rowBase = (wgid / NTN) * 256;
  const int colBase = (wgid % NTN) * 256;

  const int NT = K >> 6;  // BK = 64

  // staging source pre-swizzle: linear LDS target q within a 16 KiB unit maps
  // to global element at o = q ^ ((q>>7 & 7)<<4)  (row = o>>7, kel = (o&127)>>1)
  int s_row[2], s_kel[2];
#pragma unroll
  for (int p = 0; p < 2; ++p) {
    int q = (w * 2 + p) * 1024 + l * 16;
    int o = q ^ (((q >> 7) & 7) << 4);
    s_row[p] = o >> 7;
    s_kel[p] = (o & 127) >> 1;
  }

  auto stageA = [&](int kt, int half) {
    if (kt >= NT) return;
    char* base = smem + (kt & 1) * 65536 + half * 16384;
#pragma unroll
    for (int p = 0; p < 2; ++p) {
      int r = rowBase + half * 128 + s_row[p];
      if (r >= M) r = M - 1;
      const u16* src = A + (size_t)r * K + kt * 64 + s_kel[p];
      __builtin_amdgcn_global_load_lds(
          (const __attribute__((address_space(1))) void*)src,
          (__attribute__((address_space(3))) void*)(base + (w * 2 + p) * 1024), 16, 0, 0);
    }
  };
  auto stageB = [&](int kt, int half) {
    if (kt >= NT) return;
    char* base = smem + (kt & 1) * 65536 + 32768 + half * 16384;
#pragma unroll
    for (int p = 0; p < 2; ++p) {
      int rc = colBase + half * 128 + s_row[p];
      const u16* src = Bt + (size_t)rc * K + kt * 64 + s_kel[p];
      __builtin_amdgcn_global_load_lds(
          (const __attribute__((address_space(1))) void*)src,
          (__attribute__((address_space(3))) void*)(base + (w * 2 + p) * 1024), 16, 0, 0);
    }
  };

  f32x4 acc[8][4] = {};
  bf16x8 af[8], bq[2];

  // prologue: tile0 all 4 units + tile1 A-half0; gate tile0 (A0(1) in flight)
  stageA(0, 0); stageA(0, 1); stageB(0, 0); stageB(0, 1); stageA(1, 0);
  asm volatile("s_waitcnt vmcnt(2)" ::: "memory");
  BARX;

  const int aRow = (wm * 128 + lr) * 128;
  const int bRow = (wn * 64 + lr) * 128;
  const int ck0 = (g ^ (lr & 7)) << 4;        // kk=0 swizzled chunk
  const int ck1 = ((4 + g) ^ (lr & 7)) << 4;  // kk=1 swizzled chunk

  for (int t = 0; t < NT; ++t) {
    const char* sa = smem + (t & 1) * 65536;
    const char* sb = sa + 32768;

    // ---- ph0: kk0, ni 0-1 ----
#pragma unroll
    for (int mi = 0; mi < 8; ++mi)
      af[mi] = *(const bf16x8*)(sa + aRow + mi * 2048 + ck0);
    bq[0] = *(const bf16x8*)(sb + bRow + 0 * 2048 + ck0);
    bq[1] = *(const bf16x8*)(sb + bRow + 1 * 2048 + ck0);
    stageA(t + 1, 1);
    BARX; LGKM0;
    MFMA16(0);
    BARX;

    // ---- ph1: kk0, ni 2-3 ----
    bq[0] = *(const bf16x8*)(sb + bRow + 2 * 2048 + ck0);
    bq[1] = *(const bf16x8*)(sb + bRow + 3 * 2048 + ck0);
    stageB(t + 1, 0);
    BARX; LGKM0;
    MFMA16(2);
    BARX;

    // ---- ph2: kk1, ni 0-1 ----
#pragma unroll
    for (int mi = 0; mi < 8; ++mi)
      af[mi] = *(const bf16x8*)(sa + aRow + mi * 2048 + ck1);
    bq[0] = *(const bf16x8*)(sb + bRow + 0 * 2048 + ck1);
    bq[1] = *(const bf16x8*)(sb + bRow + 1 * 2048 + ck1);
    stageB(t + 1, 1);
    BARX; LGKM0;
    MFMA16(0);
    BARX;

    // ---- ph3: kk1, ni 2-3 ----
    bq[0] = *(const bf16x8*)(sb + bRow + 2 * 2048 + ck1);
    bq[1] = *(const bf16x8*)(sb + bRow + 3 * 2048 + ck1);
    stageA(t + 2, 0);
    BARX; LGKM0;
    MFMA16(2);
    if (t <= NT - 3)      asm volatile("s_waitcnt vmcnt(2)" ::: "memory");
    else if (t == NT - 2) asm volatile("s_waitcnt vmcnt(0)" ::: "memory");
    BARX;
  }

  // epilogue: bias + optional relu, bf16 store
  float bv[4];
#pragma unroll
  for (int ni = 0; ni < 4; ++ni) bv[ni] = bias[colBase + wn * 64 + ni * 16 + lr];
#pragma unroll
  for (int mi = 0; mi < 8; ++mi) {
#pragma unroll
    for (int r = 0; r < 4; ++r) {
      int row = rowBase + wm * 128 + mi * 16 + g * 4 + r;
      if (row < M) {
#pragma unroll
        for (int ni = 0; ni < 4; ++ni) {
          float v = acc[mi][ni][r] + bv[ni];
          if (RELU) v = fmaxf(v, 0.f);
          C[(size_t)row * Nc + colBase + wn * 64 + ni * 16 + lr] = f2bf(v);
        }
      }
    }
  }
}

// ---------------- LayerNorm + 4-head projection + sigmoid + seg-max --------
__global__ __launch_bounds__(256) void ln_att_kernel(
    const u16* __restrict__ h2, const float* __restrict__ gam,
    const float* __restrict__ bet, const float* __restrict__ Wa,
    const float* __restrict__ ba, const int* __restrict__ row,
    float* __restrict__ att, float* __restrict__ segmax, int rows) {
  const int w = threadIdx.x >> 6, l = threadIdx.x & 63;
  const int n = blockIdx.x * 4 + w;
  if (n >= rows) return;
  const u16* hp = h2 + (size_t)n * D_IN + l * 8;
  u16x8 hraw = *(const u16x8*)hp;
  float hv[8];
  float s = 0.f, sq = 0.f;
#pragma unroll
  for (int j = 0; j < 8; ++j) {
    hv[j] = bf2f(hraw[j]);
    s += hv[j];
    sq += hv[j] * hv[j];
  }
#pragma unroll
  for (int off = 32; off >= 1; off >>= 1) {
    s += __shfl_xor(s, off);
    sq += __shfl_xor(sq, off);
  }
  const float mean = s * (1.f / 512.f);
  const float var = sq * (1.f / 512.f) - mean * mean;
  const float rstd = rsqrtf(var + 1e-5f);
  float a0 = 0, a1 = 0, a2 = 0, a3 = 0;
#pragma unroll
  for (int j = 0; j < 8; ++j) {
    int d = l * 8 + j;
    float hn = (hv[j] - mean) * rstd * gam[d] + bet[d];
    f32x4 wv = *(const f32x4*)(Wa + (size_t)d * 4);
    a0 += hn * wv[0]; a1 += hn * wv[1]; a2 += hn * wv[2]; a3 += hn * wv[3];
  }
#pragma unroll
  for (int off = 32; off >= 1; off >>= 1) {
    a0 += __shfl_xor(a0, off); a1 += __shfl_xor(a1, off);
    a2 += __shfl_xor(a2, off); a3 += __shfl_xor(a3, off);
  }
  if (l == 0) {
    int rid = row[n];
    float av[4] = {a0, a1, a2, a3};
#pragma unroll
    for (int h = 0; h < 4; ++h) {
      float z = av[h] + ba[h];
      float sg = 1.f / (1.f + expf(-z));
      att[(size_t)n * 4 + h] = sg;
      atomicMax((int*)&segmax[(size_t)rid * 4 + h], __float_as_int(sg));  // sg > 0 always
    }
  }
}

// ---------------- segment sum of exp ---------------------------------------
__global__ void seg_exp_sum(const float* __restrict__ att, const int* __restrict__ row,
                            const float* __restrict__ segmax, float* __restrict__ segsum) {
  int i = blockIdx.x * 256 + threadIdx.x;
  if (i >= N_ROWS * HEADS) return;
  int n = i >> 2, h = i & 3;
  int rid = row[n];
  float ev = expf(att[i] - segmax[(size_t)rid * 4 + h]);
  atomicAdd(&segsum[(size_t)rid * 4 + h], ev);
}

// ---------------- normalize + head-mean ------------------------------------
__global__ void seg_norm(const float* __restrict__ att, const int* __restrict__ row,
                         const float* __restrict__ segmax, const float* __restrict__ segsum,
                         float* __restrict__ out) {
  int n = blockIdx.x * 256 + threadIdx.x;
  if (n >= N_ROWS) return;
  int rid = row[n];
  float s = 0.f;
#pragma unroll
  for (int h = 0; h < 4; ++h) {
    float ev = expf(att[(size_t)n * 4 + h] - segmax[(size_t)rid * 4 + h]);
    s += ev / segsum[(size_t)rid * 4 + h];
  }
  out[n] = 0.25f * s;
}

extern "C" void kernel_launch(void* const* d_in, const int* in_sizes, int n_in,
                              void* d_out, int out_size, void* d_ws, size_t ws_size,
                              hipStream_t stream) {
  const float* x = (const float*)d_in[0];
  const int* row = (const int*)d_in[1];
  const float* alpha = (const float*)d_in[2];
  const float* W1 = (const float*)d_in[3];
  const float* b1 = (const float*)d_in[4];
  const float* W2 = (const float*)d_in[5];
  const float* b2 = (const float*)d_in[6];
  const float* ln_g = (const float*)d_in[7];
  const float* ln_b = (const float*)d_in[8];
  const float* Wa = (const float*)d_in[9];
  const float* ba = (const float*)d_in[10];
  float* out = (float*)d_out;

  char* ws = (char*)d_ws;
  size_t off = 0;
  auto alloc = [&](size_t bytes) {
    void* p = ws + off;
    off += (bytes + 255) & ~(size_t)255;
    return p;
  };
  // fixed buffers (~8 MB)
  u16* W1t = (u16*)alloc((size_t)H_DIM * D_IN * 2);
  u16* W2t = (u16*)alloc((size_t)D_IN * H_DIM * 2);
  float* bias1 = (float*)alloc(H_DIM * 4);
  float* att = (float*)alloc((size_t)N_ROWS * HEADS * 4);
  float* segmax = (float*)alloc(NSEG * HEADS * 4);
  float* segsum = (float*)alloc(NSEG * HEADS * 4);

  // slab sizing from remaining ws: per-row 6144 B (xb 1KB + h1 4KB + h2 1KB)
  const size_t per_row = ((size_t)D_IN + H_DIM + D_IN) * 2;
  const size_t reserve = (size_t)1 << 20;
  size_t usable = (ws_size > off + reserve) ? (ws_size - off - reserve) : 0;
  long slab_l = (long)(usable / per_row);
  const int maxslab = (N_ROWS + 255) & ~255;  // 100096
  int slab;
  if (slab_l >= maxslab) slab = maxslab;
  else slab = (int)(slab_l & ~255L);          // round DOWN so allocs fit
  if (slab < 256) slab = 256;                 // last-resort minimum

  u16* xb = (u16*)alloc((size_t)slab * D_IN * 2);
  u16* h1 = (u16*)alloc((size_t)slab * H_DIM * 2);
  u16* h2 = (u16*)alloc((size_t)slab * D_IN * 2);

  init_misc<<<(NSEG * HEADS + 255) / 256, 256, 0, stream>>>(W1, b1, alpha, bias1, segmax, segsum);
  transpose_cast<<<dim3(H_DIM / 32, D_IN / 32), dim3(32, 8), 0, stream>>>(W1, W1t, D_IN, H_DIM);
  transpose_cast<<<dim3(D_IN / 32, H_DIM / 32), dim3(32, 8), 0, stream>>>(W2, W2t, H_DIM, D_IN);

  for (int s0 = 0; s0 < N_ROWS; s0 += slab) {
    int rows = N_ROWS - s0 < slab ? N_ROWS - s0 : slab;
    int ntm = (rows + 255) / 256;
    long n4 = (long)rows * D_IN / 4;
    cast_x_kernel<<<(int)((n4 + 255) / 256), 256, 0, stream>>>(x + (size_t)s0 * D_IN, xb, n4);
    gemm256p<1><<<ntm * (H_DIM / 256), 512, 0, stream>>>(
        xb, W1t, bias1, h1, rows, H_DIM, D_IN, H_DIM / 256);
    gemm256p<1><<<ntm * (D_IN / 256), 512, 0, stream>>>(
        h1, W2t, b2, h2, rows, D_IN, H_DIM, D_IN / 256);
    ln_att_kernel<<<(rows + 3) / 4, 256, 0, stream>>>(
        h2, ln_g, ln_b, Wa, ba, row + s0, att + (size_t)s0 * HEADS, segmax, rows);
  }

  seg_exp_sum<<<(N_ROWS * HEADS + 255) / 256, 256, 0, stream>>>(att, row, segmax, segsum);
  seg_norm<<<(N_ROWS + 255) / 256, 256, 0, stream>>>(att, row, segmax, segsum, out);
}